// Round 6
// baseline (23668.021 us; speedup 1.0000x reference)
//
#include <hip/hip_runtime.h>

#define NNODE 6144
#define FEATD 512
#define HIDD  512
#define NCLSD 64
#define LALPHA 0.2f

typedef unsigned short ushort_t;
typedef short bf16x8 __attribute__((ext_vector_type(8)));
typedef float f32x4 __attribute__((ext_vector_type(4)));

__device__ __forceinline__ float lrelu(float x){ return x > 0.f ? x : LALPHA * x; }

__device__ __forceinline__ ushort_t f2b(float x){
    union { float f; unsigned u; } v; v.f = x;
    unsigned r = v.u + 0x7fffu + ((v.u >> 16) & 1u);
    return (ushort_t)(r >> 16);
}
__device__ __forceinline__ float b2f(ushort_t u){
    union { unsigned u; float f; } v; v.u = ((unsigned)u) << 16; return v.f;
}
__device__ __forceinline__ void split2(float x, ushort_t& h, ushort_t& l){
    h = f2b(x); l = f2b(x - b2f(h));
}

// ---------------- C[M,Nc] = A[M,K] @ B[K,Nc]  (dumb fp32) ----------------
__global__ void k_mm(const float* __restrict__ A, const float* __restrict__ B,
                     float* __restrict__ C, int M, int K, int Nc){
    int idx = blockIdx.x * blockDim.x + threadIdx.x;
    if (idx >= M * Nc) return;
    int r = idx / Nc, c = idx - r * Nc;
    const float* a = A + (size_t)r * K;
    float acc = 0.f;
    for (int k = 0; k < K; k++) acc += a[k] * B[(size_t)k * Nc + c];
    C[idx] = acc;
}

// ---------------- o1/o2 = A @ {v1,v2}  (one wave per row) ----------------
__global__ void k_rowvec2_f32(const float* __restrict__ A, const float* __restrict__ v1,
                              const float* __restrict__ v2, float* __restrict__ o1,
                              float* __restrict__ o2, int K){
    int row  = (blockIdx.x * blockDim.x + threadIdx.x) >> 6;
    int lane = threadIdx.x & 63;
    const float* r = A + (size_t)row * K;
    float s1 = 0.f, s2 = 0.f;
    for (int c = lane; c < K; c += 64){ float x = r[c]; s1 += x * v1[c]; s2 += x * v2[c]; }
    #pragma unroll
    for (int m = 32; m; m >>= 1){ s1 += __shfl_xor(s1, m); s2 += __shfl_xor(s2, m); }
    if (lane == 0){ o1[row] = s1; o2[row] = s2; }
}

// ---------------- dst_{h,l}[c*R + r] = split(src[r*C + c]) ----------------
__global__ void k_transpose_split(const float* __restrict__ src, ushort_t* __restrict__ dh,
                                  ushort_t* __restrict__ dl, int R, int C){
    int idx = blockIdx.x * blockDim.x + threadIdx.x;
    if (idx >= R * C) return;
    int r = idx / C, c = idx - r * C;
    ushort_t h, l; split2(src[idx], h, l);
    dh[(size_t)c * R + r] = h; dl[(size_t)c * R + r] = l;
}

// ---------------- GAT layer 1: VALU replica of the MFMA core ----------------
// Identical structure/indexing to round-5 k_gat1_mfma; only the contraction
// instruction differs (explicit dot products under the assumed D-mapping).
__global__ __launch_bounds__(512) void k_gat1_mfma(const int* __restrict__ adj,
        const float* __restrict__ e1, const float* __restrict__ e2,
        const ushort_t* __restrict__ Vh, const ushort_t* __restrict__ Vl,
        float* __restrict__ res){
    __shared__ __align__(16) ushort_t Ph[2][16][40];
    __shared__ __align__(16) ushort_t Pl[2][16][40];
    __shared__ float mrow[16];
    __shared__ float lall[16];
    int i0 = blockIdx.x * 16;
    int tid = threadIdx.x;
    int w = tid >> 6, l = tid & 63, lm = l & 15, lh = l >> 4;
    int pr = tid >> 5, pc = tid & 31;
    int c0 = w * 64;
    const int* adjp = adj + (size_t)(i0 + pr) * NNODE;
    float e1i = e1[i0 + pr];
    // pass A: TRUE masked max for row pr
    float m = -3.0e38f;
    for (int j = pc; j < NNODE; j += 32)
        if (adjp[j] > 0) m = fmaxf(m, lrelu(e1i + e2[j]));
    #pragma unroll
    for (int o = 16; o; o >>= 1) m = fmaxf(m, __shfl_xor(m, o));
    if ((l & 31) == 0) mrow[pr] = m;
    __syncthreads();
    float M = mrow[pr];
    float lsum = 0.f;
    f32x4 acc[4] = {};
    for (int j0 = 0; j0 < NNODE; j0 += 32){
        float p = 0.f;
        if (adjp[j0 + pc] > 0) p = expf(lrelu(e1i + e2[j0 + pc]) - M);
        lsum += p;
        ushort_t h, lo; split2(p, h, lo);
        int buf = (j0 >> 5) & 1;
        Ph[buf][pr][pc] = h;
        Pl[buf][pr][pc] = lo;
        __syncthreads();
        // --- VALU replica: acc[t][r] += sum_k P[4lh+r][k] * V^T[c0+16t+lm][j0+k]
        #pragma unroll
        for (int t = 0; t < 4; t++){
            int col = c0 + t*16 + lm;
            const ushort_t* vhp = Vh + (size_t)col * NNODE + j0;
            const ushort_t* vlp = Vl + (size_t)col * NNODE + j0;
            #pragma unroll
            for (int r = 0; r < 4; r++){
                int row = lh * 4 + r;
                float s = 0.f;
                for (int k = 0; k < 32; k++){
                    float pv = b2f(Ph[buf][row][k]) + b2f(Pl[buf][row][k]);
                    float vv = b2f(vhp[k]) + b2f(vlp[k]);
                    s += pv * vv;
                }
                acc[t][r] += s;
            }
        }
    }
    #pragma unroll
    for (int o = 16; o; o >>= 1) lsum += __shfl_xor(lsum, o);
    if ((l & 31) == 0) lall[pr] = lsum;
    __syncthreads();
    #pragma unroll
    for (int t = 0; t < 4; t++){
        int col = c0 + t*16 + lm;
        #pragma unroll
        for (int r = 0; r < 4; r++){
            int row = lh * 4 + r;
            float v = acc[t][r] / lall[row];
            v = v > 0.f ? v : expm1f(v);   // elu
            res[(size_t)(i0 + row) * HIDD + col] = v;
        }
    }
}

// ---------------- GAT layer 2: VALU replica of the MFMA core ----------------
__global__ __launch_bounds__(256) void k_gat2_mfma(const int* __restrict__ adj,
        const float* __restrict__ o1, const float* __restrict__ o2,
        const float* __restrict__ t1, const float* __restrict__ t2,
        const ushort_t* __restrict__ V2h, const ushort_t* __restrict__ V2l,
        float* __restrict__ out2){
    __shared__ __align__(16) ushort_t Ph[4][2][16][40];
    __shared__ __align__(16) ushort_t Pl[4][2][16][40];
    __shared__ float accs[4][16][64];
    __shared__ float lsums[4][16];
    __shared__ float mrow[16];
    int i0 = blockIdx.x * 16;
    int tid = threadIdx.x;
    int w = tid >> 6, l = tid & 63, lm = l & 15, lh = l >> 4;
    // pass A: TRUE masked max
    {
        int mr = tid >> 4, mc = tid & 15;
        const int* ap = adj + (size_t)(i0 + mr) * NNODE;
        float o1i = o1[i0 + mr], t1i = t1[i0 + mr];
        float m = -3.0e38f;
        for (int j = mc; j < NNODE; j += 16)
            if (ap[j] > 0) m = fmaxf(m, lrelu(o1i + o2[j]) + lrelu(t1i + t2[j]));
        #pragma unroll
        for (int o = 8; o; o >>= 1) m = fmaxf(m, __shfl_xor(m, o));
        if ((l & 15) == 0) mrow[mr] = m;
    }
    __syncthreads();
    int pr = l >> 2, pcb = (l & 3) * 8;
    int jbase = w * (NNODE / 4);
    float o1v = o1[i0 + pr], t1v = t1[i0 + pr];
    float M = mrow[pr];
    float lsum = 0.f;
    f32x4 acc[4] = {};
    const int*   adjp = adj + (size_t)(i0 + pr) * NNODE + jbase + pcb;
    const float* o2p  = o2 + jbase + pcb;
    const float* t2p  = t2 + jbase + pcb;

    for (int js = 0; js < NNODE/4; js += 32){
        int4 a0 = *(const int4*)(adjp + js);
        int4 a1 = *(const int4*)(adjp + js + 4);
        float4 ov0 = *(const float4*)(o2p + js), ov1 = *(const float4*)(o2p + js + 4);
        float4 tv0 = *(const float4*)(t2p + js), tv1 = *(const float4*)(t2p + js + 4);
        int   av[8]  = {a0.x, a0.y, a0.z, a0.w, a1.x, a1.y, a1.z, a1.w};
        float o2a[8] = {ov0.x, ov0.y, ov0.z, ov0.w, ov1.x, ov1.y, ov1.z, ov1.w};
        float t2a[8] = {tv0.x, tv0.y, tv0.z, tv0.w, tv1.x, tv1.y, tv1.z, tv1.w};
        bf16x8 pkh, pkl;
        #pragma unroll
        for (int e = 0; e < 8; e++){
            float p = 0.f;
            if (av[e] > 0) p = expf(lrelu(o1v + o2a[e]) + lrelu(t1v + t2a[e]) - M);
            lsum += p;
            ushort_t h, lo; split2(p, h, lo);
            ((ushort_t*)&pkh)[e] = h; ((ushort_t*)&pkl)[e] = lo;
        }
        int buf = (js >> 5) & 1;
        *(bf16x8*)&Ph[w][buf][pr][pcb] = pkh;
        *(bf16x8*)&Pl[w][buf][pr][pcb] = pkl;
        __syncthreads();
        // --- VALU replica: acc[t][r] += sum_k P[4lh+r][k] * V2^T[16t+lm][jbase+js+k]
        #pragma unroll
        for (int t = 0; t < 4; t++){
            int col = t*16 + lm;
            const ushort_t* vhp = V2h + (size_t)col * NNODE + jbase + js;
            const ushort_t* vlp = V2l + (size_t)col * NNODE + jbase + js;
            #pragma unroll
            for (int r = 0; r < 4; r++){
                int row = lh * 4 + r;
                float s = 0.f;
                for (int k = 0; k < 32; k++){
                    float pv = b2f(Ph[w][buf][row][k]) + b2f(Pl[w][buf][row][k]);
                    float vv = b2f(vhp[k]) + b2f(vlp[k]);
                    s += pv * vv;
                }
                acc[t][r] += s;
            }
        }
    }
    lsum += __shfl_xor(lsum, 1);
    lsum += __shfl_xor(lsum, 2);
    if ((l & 3) == 0) lsums[w][pr] = lsum;
    #pragma unroll
    for (int t = 0; t < 4; t++)
        #pragma unroll
        for (int r = 0; r < 4; r++)
            accs[w][lh*4 + r][t*16 + lm] = acc[t][r];
    __syncthreads();
    #pragma unroll
    for (int rr = 0; rr < 4; rr++){
        int row = w * 4 + rr;
        float den = lsums[0][row] + lsums[1][row] + lsums[2][row] + lsums[3][row];
        float v = (accs[0][row][l] + accs[1][row][l] + accs[2][row][l] + accs[3][row][l]) / den;
        out2[(size_t)(i0 + row) * NCLSD + l] = v;
    }
}

// ---------------- row-wise log_softmax over 64 classes (one wave/row) ----------------
__global__ void k_logsoftmax(const float* __restrict__ out2, float* __restrict__ out){
    int w = threadIdx.x >> 6, l = threadIdx.x & 63;
    int row = blockIdx.x * 4 + w;
    float v = out2[(size_t)row * NCLSD + l];
    float mx = v;
    #pragma unroll
    for (int o = 32; o; o >>= 1) mx = fmaxf(mx, __shfl_xor(mx, o));
    float ex = expf(v - mx);
    #pragma unroll
    for (int o = 32; o; o >>= 1) ex += __shfl_xor(ex, o);
    out[(size_t)row * NCLSD + l] = v - mx - logf(ex);
}

// ---------------- launch (identical to round 5) ----------------
extern "C" void kernel_launch(void* const* d_in, const int* in_sizes, int n_in,
                              void* d_out, int out_size, void* d_ws, size_t ws_size,
                              hipStream_t stream){
    const float* X   = (const float*)d_in[0];
    const int*   adj = (const int*)d_in[1];
    const float* Wg  = (const float*)d_in[2];
    const float* ag  = (const float*)d_in[3];
    const float* Wt  = (const float*)d_in[4];
    const float* at  = (const float*)d_in[5];
    const float* Wo  = (const float*)d_in[6];
    const float* ao  = (const float*)d_in[7];
    float* out = (float*)d_out;

    char* ws = (char*)d_ws;
    size_t off = 0;
    auto take = [&](size_t n){ char* p = ws + off; off = (off + n + 255) & ~(size_t)255; return p; };
    float* bufA = (float*)take((size_t)NNODE * HIDD * 4);
    ushort_t* WhTh = (ushort_t*)take((size_t)HIDD * NNODE * 2);
    ushort_t* WhTl = (ushort_t*)take((size_t)HIDD * NNODE * 2);
    float* bufE = (float*)take((size_t)NNODE * NCLSD * 4);
    ushort_t* Wh2Th = (ushort_t*)take((size_t)NCLSD * NNODE * 2);
    ushort_t* Wh2Tl = (ushort_t*)take((size_t)NCLSD * NNODE * 2);
    float* e1v  = (float*)take(NNODE * 4);
    float* e2v  = (float*)take(NNODE * 4);
    float* t1v  = (float*)take(NNODE * 4);
    float* t2v  = (float*)take(NNODE * 4);
    float* o1v  = (float*)take(NNODE * 4);
    float* o2v  = (float*)take(NNODE * 4);

    float* Wh1 = bufA;
    float* res = bufA;
    float* Wht = (float*)WhTh;
    float* Wh2 = bufE;
    float* out2 = bufE;

    k_mm<<<dim3((NNODE*HIDD)/256), dim3(256), 0, stream>>>(X, Wg, Wh1, NNODE, FEATD, HIDD);
    k_rowvec2_f32<<<dim3(NNODE/4), dim3(256), 0, stream>>>(Wh1, ag, ag + HIDD, e1v, e2v, HIDD);
    k_transpose_split<<<dim3((NNODE*HIDD + 255)/256), dim3(256), 0, stream>>>(Wh1, WhTh, WhTl, NNODE, HIDD);
    k_gat1_mfma<<<dim3(NNODE/16), dim3(512), 0, stream>>>(adj, e1v, e2v, WhTh, WhTl, res);
    k_mm<<<dim3((NNODE*HIDD)/256), dim3(256), 0, stream>>>(res, Wt, Wht, NNODE, HIDD, HIDD);
    k_rowvec2_f32<<<dim3(NNODE/4), dim3(256), 0, stream>>>(Wht, at, at + HIDD, t1v, t2v, HIDD);
    k_mm<<<dim3((NNODE*NCLSD)/256), dim3(256), 0, stream>>>(res, Wo, Wh2, NNODE, HIDD, NCLSD);
    k_rowvec2_f32<<<dim3(NNODE/4), dim3(256), 0, stream>>>(Wh2, ao, ao + NCLSD, o1v, o2v, NCLSD);
    k_transpose_split<<<dim3((NNODE*NCLSD + 255)/256), dim3(256), 0, stream>>>(Wh2, Wh2Th, Wh2Tl, NNODE, NCLSD);
    k_gat2_mfma<<<dim3(NNODE/16), dim3(256), 0, stream>>>(adj, o1v, o2v, t1v, t2v, Wh2Th, Wh2Tl, out2);
    k_logsoftmax<<<dim3(NNODE/4), dim3(256), 0, stream>>>(out2, out);
}

// Round 8
// 2335.894 us; speedup vs baseline: 10.1323x; 10.1323x over previous
//
#include <hip/hip_runtime.h>

#define NNODE 6144
#define FEATD 512
#define HIDD  512
#define NCLSD 64
#define LALPHA 0.2f

typedef unsigned short ushort_t;
typedef short bf16x8 __attribute__((ext_vector_type(8)));
typedef float f32x4 __attribute__((ext_vector_type(4)));

__device__ __forceinline__ float lrelu(float x){ return x > 0.f ? x : LALPHA * x; }

__device__ __forceinline__ ushort_t f2b(float x){
    union { float f; unsigned u; } v; v.f = x;
    unsigned r = v.u + 0x7fffu + ((v.u >> 16) & 1u);
    return (ushort_t)(r >> 16);
}
__device__ __forceinline__ float b2f(ushort_t u){
    union { unsigned u; float f; } v; v.u = ((unsigned)u) << 16; return v.f;
}
__device__ __forceinline__ void split2(float x, ushort_t& h, ushort_t& l){
    h = f2b(x); l = f2b(x - b2f(h));
}

// Runtime C/D-layout calibration: decodes, for this instruction, which
// (P-row, V-col) lands in output slot (lane, reg). Exact in bf16/fp32.
__device__ __forceinline__ void calib_cd(int lm, int* qrow, int* vcol){
    bf16x8 ai, as;
    ushort_t vi = f2b((float)(lm + 1));   // row/col key, exact (<=16)
    ushort_t vs = f2b(0.03125f);          // 1/32, exact
    #pragma unroll
    for (int e = 0; e < 8; e++){ ((ushort_t*)&ai)[e] = vi; ((ushort_t*)&as)[e] = vs; }
    f32x4 z = {0.f, 0.f, 0.f, 0.f};
    f32x4 d1 = __builtin_amdgcn_mfma_f32_16x16x32_bf16(ai, as, z, 0, 0, 0); // = P-row+1
    f32x4 d2 = __builtin_amdgcn_mfma_f32_16x16x32_bf16(as, ai, z, 0, 0, 0); // = V-col+1
    #pragma unroll
    for (int r = 0; r < 4; r++){
        qrow[r] = (int)(d1[r] + 0.5f) - 1;
        vcol[r] = (int)(d2[r] + 0.5f) - 1;
    }
}

// ---------------- C[M,Nc] = A[M,K] @ B[K,Nc]  (dumb fp32) ----------------
__global__ void k_mm(const float* __restrict__ A, const float* __restrict__ B,
                     float* __restrict__ C, int M, int K, int Nc){
    int idx = blockIdx.x * blockDim.x + threadIdx.x;
    if (idx >= M * Nc) return;
    int r = idx / Nc, c = idx - r * Nc;
    const float* a = A + (size_t)r * K;
    float acc = 0.f;
    for (int k = 0; k < K; k++) acc += a[k] * B[(size_t)k * Nc + c];
    C[idx] = acc;
}

// ---------------- o1/o2 = A @ {v1,v2}  (one wave per row) ----------------
__global__ void k_rowvec2_f32(const float* __restrict__ A, const float* __restrict__ v1,
                              const float* __restrict__ v2, float* __restrict__ o1,
                              float* __restrict__ o2, int K){
    int row  = (blockIdx.x * blockDim.x + threadIdx.x) >> 6;
    int lane = threadIdx.x & 63;
    const float* r = A + (size_t)row * K;
    float s1 = 0.f, s2 = 0.f;
    for (int c = lane; c < K; c += 64){ float x = r[c]; s1 += x * v1[c]; s2 += x * v2[c]; }
    #pragma unroll
    for (int m = 32; m; m >>= 1){ s1 += __shfl_xor(s1, m); s2 += __shfl_xor(s2, m); }
    if (lane == 0){ o1[row] = s1; o2[row] = s2; }
}

// ---------------- dst_{h,l}[c*R + r] = split(src[r*C + c]) ----------------
__global__ void k_transpose_split(const float* __restrict__ src, ushort_t* __restrict__ dh,
                                  ushort_t* __restrict__ dl, int R, int C){
    int idx = blockIdx.x * blockDim.x + threadIdx.x;
    if (idx >= R * C) return;
    int r = idx / C, c = idx - r * C;
    ushort_t h, l; split2(src[idx], h, l);
    dh[(size_t)c * R + r] = h; dl[(size_t)c * R + r] = l;
}

// ---------------- GAT layer 1: MFMA core + calibrated epilogue ----------------
__global__ __launch_bounds__(512) void k_gat1_mfma(const int* __restrict__ adj,
        const float* __restrict__ e1, const float* __restrict__ e2,
        const ushort_t* __restrict__ Vh, const ushort_t* __restrict__ Vl,
        float* __restrict__ res){
    __shared__ __align__(16) ushort_t Ph[2][16][40];
    __shared__ __align__(16) ushort_t Pl[2][16][40];
    __shared__ float mrow[16];
    __shared__ float lall[16];
    int i0 = blockIdx.x * 16;
    int tid = threadIdx.x;
    int w = tid >> 6, l = tid & 63, lm = l & 15, lh = l >> 4;
    int pr = tid >> 5, pc = tid & 31;
    int c0 = w * 64;
    int qrow[4], vcol[4];
    calib_cd(lm, qrow, vcol);
    const int* adjp = adj + (size_t)(i0 + pr) * NNODE;
    float e1i = e1[i0 + pr];
    // pass A: TRUE masked max for row pr
    float m = -3.0e38f;
    for (int j = pc; j < NNODE; j += 32)
        if (adjp[j] > 0) m = fmaxf(m, lrelu(e1i + e2[j]));
    #pragma unroll
    for (int o = 16; o; o >>= 1) m = fmaxf(m, __shfl_xor(m, o));
    if ((l & 31) == 0) mrow[pr] = m;
    __syncthreads();
    float M = mrow[pr];
    float lsum = 0.f;
    f32x4 acc[4] = {};
    for (int j0 = 0; j0 < NNODE; j0 += 32){
        float p = 0.f;
        if (adjp[j0 + pc] > 0) p = expf(lrelu(e1i + e2[j0 + pc]) - M);
        lsum += p;
        ushort_t h, lo; split2(p, h, lo);
        int buf = (j0 >> 5) & 1;
        Ph[buf][pr][pc] = h;
        Pl[buf][pr][pc] = lo;
        __syncthreads();
        bf16x8 ah = *(const bf16x8*)&Ph[buf][lm][lh * 8];
        bf16x8 al = *(const bf16x8*)&Pl[buf][lm][lh * 8];
        #pragma unroll
        for (int t = 0; t < 4; t++){
            size_t boff = (size_t)(c0 + t*16 + lm) * NNODE + j0 + lh * 8;
            bf16x8 vh = *(const bf16x8*)(Vh + boff);
            bf16x8 vl = *(const bf16x8*)(Vl + boff);
            acc[t] = __builtin_amdgcn_mfma_f32_16x16x32_bf16(ah, vh, acc[t], 0, 0, 0);
            acc[t] = __builtin_amdgcn_mfma_f32_16x16x32_bf16(ah, vl, acc[t], 0, 0, 0);
            acc[t] = __builtin_amdgcn_mfma_f32_16x16x32_bf16(al, vh, acc[t], 0, 0, 0);
        }
    }
    #pragma unroll
    for (int o = 16; o; o >>= 1) lsum += __shfl_xor(lsum, o);
    if ((l & 31) == 0) lall[pr] = lsum;
    __syncthreads();
    // calibrated epilogue: decoded (P-row, V-col) per (lane, reg)
    #pragma unroll
    for (int t = 0; t < 4; t++){
        #pragma unroll
        for (int r = 0; r < 4; r++){
            int row = qrow[r];
            int col = c0 + t*16 + vcol[r];
            float v = acc[t][r] / lall[row];
            v = v > 0.f ? v : expm1f(v);   // elu
            res[(size_t)(i0 + row) * HIDD + col] = v;
        }
    }
}

// ---------------- GAT layer 2: barrier-free MFMA clone + calibrated epilogue ----------------
// 256 thr (4 waves), 16 rows/block; wave = j-quarter. Each lane computes the 8
// P-values its own A-fragment needs (row = lm, cols jbase+js+8*lh+e) directly
// in registers: no P LDS, no in-loop barriers. Combine logic = round-6 replica.
__global__ __launch_bounds__(256) void k_gat2_mfma(const int* __restrict__ adj,
        const float* __restrict__ o1, const float* __restrict__ o2,
        const float* __restrict__ t1, const float* __restrict__ t2,
        const ushort_t* __restrict__ V2h, const ushort_t* __restrict__ V2l,
        float* __restrict__ out2){
    __shared__ float accs[4][16][64];
    __shared__ float lsums[4][16];
    __shared__ float mrow[16];
    int i0 = blockIdx.x * 16;
    int tid = threadIdx.x;
    int w = tid >> 6, l = tid & 63, lm = l & 15, lh = l >> 4;
    // pass A: TRUE masked max (round-6 validated)
    {
        int mr = tid >> 4, mc = tid & 15;
        const int* ap = adj + (size_t)(i0 + mr) * NNODE;
        float o1i = o1[i0 + mr], t1i = t1[i0 + mr];
        float m = -3.0e38f;
        for (int j = mc; j < NNODE; j += 16)
            if (ap[j] > 0) m = fmaxf(m, lrelu(o1i + o2[j]) + lrelu(t1i + t2[j]));
        #pragma unroll
        for (int o = 8; o; o >>= 1) m = fmaxf(m, __shfl_xor(m, o));
        if ((l & 15) == 0) mrow[mr] = m;
    }
    __syncthreads();
    int qrow[4], vcol[4];
    calib_cd(lm, qrow, vcol);
    int jbase = w * (NNODE / 4);
    float o1v = o1[i0 + lm], t1v = t1[i0 + lm];
    float M = mrow[lm];
    float lsum = 0.f;
    f32x4 acc[4] = {};
    const int*   adjp = adj + (size_t)(i0 + lm) * NNODE + jbase + lh * 8;
    const float* o2p  = o2 + jbase + lh * 8;
    const float* t2p  = t2 + jbase + lh * 8;

    for (int js = 0; js < NNODE/4; js += 32){
        int4 a0 = *(const int4*)(adjp + js);
        int4 a1 = *(const int4*)(adjp + js + 4);
        float4 ov0 = *(const float4*)(o2p + js), ov1 = *(const float4*)(o2p + js + 4);
        float4 tv0 = *(const float4*)(t2p + js), tv1 = *(const float4*)(t2p + js + 4);
        int   av[8]  = {a0.x, a0.y, a0.z, a0.w, a1.x, a1.y, a1.z, a1.w};
        float o2a[8] = {ov0.x, ov0.y, ov0.z, ov0.w, ov1.x, ov1.y, ov1.z, ov1.w};
        float t2a[8] = {tv0.x, tv0.y, tv0.z, tv0.w, tv1.x, tv1.y, tv1.z, tv1.w};
        bf16x8 pkh, pkl;
        #pragma unroll
        for (int e = 0; e < 8; e++){
            float p = 0.f;
            if (av[e] > 0) p = expf(lrelu(o1v + o2a[e]) + lrelu(t1v + t2a[e]) - M);
            lsum += p;
            ushort_t h, lo; split2(p, h, lo);
            ((ushort_t*)&pkh)[e] = h; ((ushort_t*)&pkl)[e] = lo;
        }
        #pragma unroll
        for (int t = 0; t < 4; t++){
            size_t boff = (size_t)(t*16 + lm) * NNODE + jbase + js + lh * 8;
            bf16x8 vh = *(const bf16x8*)(V2h + boff);
            bf16x8 vl = *(const bf16x8*)(V2l + boff);
            acc[t] = __builtin_amdgcn_mfma_f32_16x16x32_bf16(pkh, vh, acc[t], 0, 0, 0);
            acc[t] = __builtin_amdgcn_mfma_f32_16x16x32_bf16(pkh, vl, acc[t], 0, 0, 0);
            acc[t] = __builtin_amdgcn_mfma_f32_16x16x32_bf16(pkl, vh, acc[t], 0, 0, 0);
        }
    }
    // row sums: lanes {l, l^16, l^32, l^48} share row lm
    lsum += __shfl_xor(lsum, 16);
    lsum += __shfl_xor(lsum, 32);
    if (lh == 0) lsums[w][lm] = lsum;
    #pragma unroll
    for (int t = 0; t < 4; t++)
        #pragma unroll
        for (int r = 0; r < 4; r++)
            accs[w][qrow[r]][t*16 + vcol[r]] = acc[t][r];
    __syncthreads();
    #pragma unroll
    for (int rr = 0; rr < 4; rr++){
        int row = w * 4 + rr;
        float den = lsums[0][row] + lsums[1][row] + lsums[2][row] + lsums[3][row];
        float v = (accs[0][row][l] + accs[1][row][l] + accs[2][row][l] + accs[3][row][l]) / den;
        out2[(size_t)(i0 + row) * NCLSD + l] = v;
    }
}

// ---------------- row-wise log_softmax over 64 classes (one wave/row) ----------------
__global__ void k_logsoftmax(const float* __restrict__ out2, float* __restrict__ out){
    int w = threadIdx.x >> 6, l = threadIdx.x & 63;
    int row = blockIdx.x * 4 + w;
    float v = out2[(size_t)row * NCLSD + l];
    float mx = v;
    #pragma unroll
    for (int o = 32; o; o >>= 1) mx = fmaxf(mx, __shfl_xor(mx, o));
    float ex = expf(v - mx);
    #pragma unroll
    for (int o = 32; o; o >>= 1) ex += __shfl_xor(ex, o);
    out[(size_t)row * NCLSD + l] = v - mx - logf(ex);
}

// ---------------- launch (identical to round 6) ----------------
extern "C" void kernel_launch(void* const* d_in, const int* in_sizes, int n_in,
                              void* d_out, int out_size, void* d_ws, size_t ws_size,
                              hipStream_t stream){
    const float* X   = (const float*)d_in[0];
    const int*   adj = (const int*)d_in[1];
    const float* Wg  = (const float*)d_in[2];
    const float* ag  = (const float*)d_in[3];
    const float* Wt  = (const float*)d_in[4];
    const float* at  = (const float*)d_in[5];
    const float* Wo  = (const float*)d_in[6];
    const float* ao  = (const float*)d_in[7];
    float* out = (float*)d_out;

    char* ws = (char*)d_ws;
    size_t off = 0;
    auto take = [&](size_t n){ char* p = ws + off; off = (off + n + 255) & ~(size_t)255; return p; };
    float* bufA = (float*)take((size_t)NNODE * HIDD * 4);
    ushort_t* WhTh = (ushort_t*)take((size_t)HIDD * NNODE * 2);
    ushort_t* WhTl = (ushort_t*)take((size_t)HIDD * NNODE * 2);
    float* bufE = (float*)take((size_t)NNODE * NCLSD * 4);
    ushort_t* Wh2Th = (ushort_t*)take((size_t)NCLSD * NNODE * 2);
    ushort_t* Wh2Tl = (ushort_t*)take((size_t)NCLSD * NNODE * 2);
    float* e1v  = (float*)take(NNODE * 4);
    float* e2v  = (float*)take(NNODE * 4);
    float* t1v  = (float*)take(NNODE * 4);
    float* t2v  = (float*)take(NNODE * 4);
    float* o1v  = (float*)take(NNODE * 4);
    float* o2v  = (float*)take(NNODE * 4);

    float* Wh1 = bufA;
    float* res = bufA;
    float* Wht = (float*)WhTh;
    float* Wh2 = bufE;
    float* out2 = bufE;

    k_mm<<<dim3((NNODE*HIDD)/256), dim3(256), 0, stream>>>(X, Wg, Wh1, NNODE, FEATD, HIDD);
    k_rowvec2_f32<<<dim3(NNODE/4), dim3(256), 0, stream>>>(Wh1, ag, ag + HIDD, e1v, e2v, HIDD);
    k_transpose_split<<<dim3((NNODE*HIDD + 255)/256), dim3(256), 0, stream>>>(Wh1, WhTh, WhTl, NNODE, HIDD);
    k_gat1_mfma<<<dim3(NNODE/16), dim3(512), 0, stream>>>(adj, e1v, e2v, WhTh, WhTl, res);
    k_mm<<<dim3((NNODE*HIDD)/256), dim3(256), 0, stream>>>(res, Wt, Wht, NNODE, HIDD, HIDD);
    k_rowvec2_f32<<<dim3(NNODE/4), dim3(256), 0, stream>>>(Wht, at, at + HIDD, t1v, t2v, HIDD);
    k_mm<<<dim3((NNODE*NCLSD)/256), dim3(256), 0, stream>>>(res, Wo, Wh2, NNODE, HIDD, NCLSD);
    k_rowvec2_f32<<<dim3(NNODE/4), dim3(256), 0, stream>>>(Wh2, ao, ao + NCLSD, o1v, o2v, NCLSD);
    k_transpose_split<<<dim3((NNODE*NCLSD + 255)/256), dim3(256), 0, stream>>>(Wh2, Wh2Th, Wh2Tl, NNODE, NCLSD);
    k_gat2_mfma<<<dim3(NNODE/16), dim3(256), 0, stream>>>(adj, o1v, o2v, t1v, t2v, Wh2Th, Wh2Tl, out2);
    k_logsoftmax<<<dim3(NNODE/4), dim3(256), 0, stream>>>(out2, out);
}

// Round 9
// 949.438 us; speedup vs baseline: 24.9284x; 2.4603x over previous
//
#include <hip/hip_runtime.h>

#define NNODE 6144
#define FEATD 512
#define HIDD  512
#define NCLSD 64
#define LALPHA 0.2f

typedef unsigned short ushort_t;
typedef short bf16x8 __attribute__((ext_vector_type(8)));
typedef float f32x4 __attribute__((ext_vector_type(4)));

__device__ __forceinline__ float lrelu(float x){ return x > 0.f ? x : LALPHA * x; }

__device__ __forceinline__ ushort_t f2b(float x){
    union { float f; unsigned u; } v; v.f = x;
    unsigned r = v.u + 0x7fffu + ((v.u >> 16) & 1u);
    return (ushort_t)(r >> 16);
}
__device__ __forceinline__ float b2f(ushort_t u){
    union { unsigned u; float f; } v; v.u = ((unsigned)u) << 16; return v.f;
}
__device__ __forceinline__ void split2(float x, ushort_t& h, ushort_t& l){
    h = f2b(x); l = f2b(x - b2f(h));
}

// Runtime C/D-layout calibration (round-8 validated): decodes which
// (A-row, B-col) lands in output slot (lane, reg).
__device__ __forceinline__ void calib_cd(int lm, int* qrow, int* vcol){
    bf16x8 ai, as;
    ushort_t vi = f2b((float)(lm + 1));
    ushort_t vs = f2b(0.03125f);
    #pragma unroll
    for (int e = 0; e < 8; e++){ ((ushort_t*)&ai)[e] = vi; ((ushort_t*)&as)[e] = vs; }
    f32x4 z = {0.f, 0.f, 0.f, 0.f};
    f32x4 d1 = __builtin_amdgcn_mfma_f32_16x16x32_bf16(ai, as, z, 0, 0, 0);
    f32x4 d2 = __builtin_amdgcn_mfma_f32_16x16x32_bf16(as, ai, z, 0, 0, 0);
    #pragma unroll
    for (int r = 0; r < 4; r++){
        qrow[r] = (int)(d1[r] + 0.5f) - 1;
        vcol[r] = (int)(d2[r] + 0.5f) - 1;
    }
}

// ---------------- C[M,Nc] = A[M,K] @ B[K,Nc]  (dumb fp32, only small uses) ----------------
__global__ void k_mm(const float* __restrict__ A, const float* __restrict__ B,
                     float* __restrict__ C, int M, int K, int Nc){
    int idx = blockIdx.x * blockDim.x + threadIdx.x;
    if (idx >= M * Nc) return;
    int r = idx / Nc, c = idx - r * Nc;
    const float* a = A + (size_t)r * K;
    float acc = 0.f;
    for (int k = 0; k < K; k++) acc += a[k] * B[(size_t)k * Nc + c];
    C[idx] = acc;
}

// out1[r]=sum_c W[r][c]*a[c]; out2[r]=sum_c W[r][c]*a[K+c]  (one wave per row)
__global__ void k_fold(const float* __restrict__ W, const float* __restrict__ a,
                       float* __restrict__ out1, float* __restrict__ out2, int K){
    int row  = (blockIdx.x * blockDim.x + threadIdx.x) >> 6;
    int lane = threadIdx.x & 63;
    const float* wr = W + (size_t)row * K;
    float s1 = 0.f, s2 = 0.f;
    for (int c = lane; c < K; c += 64){ float w = wr[c]; s1 += w * a[c]; s2 += w * a[K + c]; }
    #pragma unroll
    for (int m = 32; m; m >>= 1){ s1 += __shfl_xor(s1, m); s2 += __shfl_xor(s2, m); }
    if (lane == 0){ out1[row] = s1; out2[row] = s2; }
}

// ---------------- o1/o2 = A @ {v1,v2}  (one wave per row) ----------------
__global__ void k_rowvec2_f32(const float* __restrict__ A, const float* __restrict__ v1,
                              const float* __restrict__ v2, float* __restrict__ o1,
                              float* __restrict__ o2, int K){
    int row  = (blockIdx.x * blockDim.x + threadIdx.x) >> 6;
    int lane = threadIdx.x & 63;
    const float* r = A + (size_t)row * K;
    float s1 = 0.f, s2 = 0.f;
    for (int c = lane; c < K; c += 64){ float x = r[c]; s1 += x * v1[c]; s2 += x * v2[c]; }
    #pragma unroll
    for (int m = 32; m; m >>= 1){ s1 += __shfl_xor(s1, m); s2 += __shfl_xor(s2, m); }
    if (lane == 0){ o1[row] = s1; o2[row] = s2; }
}

// ---------------- dst_{h,l}[c*R + r] = split(src[r*C + c]) ----------------
__global__ void k_transpose_split(const float* __restrict__ src, ushort_t* __restrict__ dh,
                                  ushort_t* __restrict__ dl, int R, int C){
    int idx = blockIdx.x * blockDim.x + threadIdx.x;
    if (idx >= R * C) return;
    int r = idx / C, c = idx - r * C;
    ushort_t h, l; split2(src[idx], h, l);
    dh[(size_t)c * R + r] = h; dl[(size_t)c * R + r] = l;
}

// ---------------- *out = max(x[0..n)) ----------------
__global__ void k_max(const float* __restrict__ x, int n, float* __restrict__ out){
    __shared__ float sm[16];
    float m = -3.0e38f;
    for (int i = threadIdx.x; i < n; i += blockDim.x) m = fmaxf(m, x[i]);
    #pragma unroll
    for (int s = 32; s; s >>= 1) m = fmaxf(m, __shfl_xor(m, s));
    if ((threadIdx.x & 63) == 0) sm[threadIdx.x >> 6] = m;
    __syncthreads();
    if (threadIdx.x == 0){
        float mm = sm[0];
        for (int i = 1; i < (int)(blockDim.x >> 6); i++) mm = fmaxf(mm, sm[i]);
        *out = mm;
    }
}

// ---------------- Wh1^T = (X @ Wg)^T  via MFMA, hi/lo out [HIDD][NNODE] ----------------
// 512 thr (8 waves), 16 X-rows/block, wave w -> 64 Wg-cols; calibrated epilogue.
__global__ __launch_bounds__(512) void k_gemm_xw(const float* __restrict__ X,
        const ushort_t* __restrict__ Bh, const ushort_t* __restrict__ Bl,
        ushort_t* __restrict__ WhTh, ushort_t* __restrict__ WhTl){
    int i0 = blockIdx.x * 16;
    int w = threadIdx.x >> 6, l = threadIdx.x & 63, lm = l & 15, lh = l >> 4;
    int c0 = w * 64;
    int qrow[4], vcol[4];
    calib_cd(lm, qrow, vcol);
    f32x4 acc[4] = {};
    const float* xp = X + (size_t)(i0 + lm) * FEATD + lh * 8;
    for (int k0 = 0; k0 < FEATD; k0 += 32){
        bf16x8 ah, al;
        #pragma unroll
        for (int e = 0; e < 8; e++){
            ushort_t h, lo; split2(xp[k0 + e], h, lo);
            ((ushort_t*)&ah)[e] = h; ((ushort_t*)&al)[e] = lo;
        }
        #pragma unroll
        for (int t = 0; t < 4; t++){
            size_t boff = (size_t)(c0 + t*16 + lm) * FEATD + k0 + lh * 8;
            bf16x8 bh = *(const bf16x8*)(Bh + boff);
            bf16x8 bl = *(const bf16x8*)(Bl + boff);
            acc[t] = __builtin_amdgcn_mfma_f32_16x16x32_bf16(ah, bh, acc[t], 0, 0, 0);
            acc[t] = __builtin_amdgcn_mfma_f32_16x16x32_bf16(ah, bl, acc[t], 0, 0, 0);
            acc[t] = __builtin_amdgcn_mfma_f32_16x16x32_bf16(al, bh, acc[t], 0, 0, 0);
        }
    }
    #pragma unroll
    for (int t = 0; t < 4; t++){
        #pragma unroll
        for (int r = 0; r < 4; r++){
            int col = c0 + t*16 + vcol[r];
            int row = i0 + qrow[r];
            ushort_t h, lo; split2(acc[t][r], h, lo);
            size_t o = (size_t)col * NNODE + row;
            WhTh[o] = h; WhTl[o] = lo;
        }
    }
}

// ---------------- GAT layer 1 v2: bound-max single pass, KVBLK=64, col-split ----------------
// 256 thr (4 waves); block = (row-group rg, col-half ch): 16 rows x 256 cols.
__global__ __launch_bounds__(256) void k_gat1(const int* __restrict__ adj,
        const float* __restrict__ e1, const float* __restrict__ e2,
        const float* __restrict__ e2max,
        const ushort_t* __restrict__ Vh, const ushort_t* __restrict__ Vl,
        float* __restrict__ res){
    __shared__ __align__(16) ushort_t Ph[2][16][72];
    __shared__ __align__(16) ushort_t Pl[2][16][72];
    __shared__ float lall[16];
    int bid = blockIdx.x;
    int rg = bid >> 1, ch = bid & 1;
    int i0 = rg * 16;
    int tid = threadIdx.x;
    int w = tid >> 6, l = tid & 63, lm = l & 15, lh = l >> 4;
    int cbase = ch * 256 + w * 64;
    int pr = tid >> 4, jc = (tid & 15) * 4;       // P-gen: 4 cols per thread
    int qrow[4], vcol[4];
    calib_cd(lm, qrow, vcol);
    float e1i = e1[i0 + pr];
    float M = lrelu(e1i + *e2max);                // exact upper bound (softmax-invariant)
    float lsum = 0.f;
    f32x4 acc[4][2] = {};
    const int* adjp = adj + (size_t)(i0 + pr) * NNODE + jc;
    const float* e2p = e2 + jc;

    for (int j0 = 0; j0 < NNODE; j0 += 64){
        int buf = (j0 >> 6) & 1;
        int4   a4 = *(const int4*)(adjp + j0);
        float4 f4 = *(const float4*)(e2p + j0);
        float p0 = (a4.x > 0) ? expf(lrelu(e1i + f4.x) - M) : 0.f;
        float p1 = (a4.y > 0) ? expf(lrelu(e1i + f4.y) - M) : 0.f;
        float p2 = (a4.z > 0) ? expf(lrelu(e1i + f4.z) - M) : 0.f;
        float p3 = (a4.w > 0) ? expf(lrelu(e1i + f4.w) - M) : 0.f;
        lsum += (p0 + p1) + (p2 + p3);
        union { ushort_t u[4]; uint2 v; } ph, pl;
        split2(p0, ph.u[0], pl.u[0]); split2(p1, ph.u[1], pl.u[1]);
        split2(p2, ph.u[2], pl.u[2]); split2(p3, ph.u[3], pl.u[3]);
        *(uint2*)&Ph[buf][pr][jc] = ph.v;
        *(uint2*)&Pl[buf][pr][jc] = pl.v;
        __syncthreads();
        bf16x8 ah0 = *(const bf16x8*)&Ph[buf][lm][lh * 8];
        bf16x8 al0 = *(const bf16x8*)&Pl[buf][lm][lh * 8];
        bf16x8 ah1 = *(const bf16x8*)&Ph[buf][lm][32 + lh * 8];
        bf16x8 al1 = *(const bf16x8*)&Pl[buf][lm][32 + lh * 8];
        #pragma unroll
        for (int t = 0; t < 4; t++){
            size_t boff = (size_t)(cbase + t*16 + lm) * NNODE + j0 + lh * 8;
            bf16x8 vh0 = *(const bf16x8*)(Vh + boff);
            bf16x8 vl0 = *(const bf16x8*)(Vl + boff);
            bf16x8 vh1 = *(const bf16x8*)(Vh + boff + 32);
            bf16x8 vl1 = *(const bf16x8*)(Vl + boff + 32);
            acc[t][0] = __builtin_amdgcn_mfma_f32_16x16x32_bf16(ah0, vh0, acc[t][0], 0, 0, 0);
            acc[t][0] = __builtin_amdgcn_mfma_f32_16x16x32_bf16(ah0, vl0, acc[t][0], 0, 0, 0);
            acc[t][0] = __builtin_amdgcn_mfma_f32_16x16x32_bf16(al0, vh0, acc[t][0], 0, 0, 0);
            acc[t][1] = __builtin_amdgcn_mfma_f32_16x16x32_bf16(ah1, vh1, acc[t][1], 0, 0, 0);
            acc[t][1] = __builtin_amdgcn_mfma_f32_16x16x32_bf16(ah1, vl1, acc[t][1], 0, 0, 0);
            acc[t][1] = __builtin_amdgcn_mfma_f32_16x16x32_bf16(al1, vh1, acc[t][1], 0, 0, 0);
        }
    }
    // lsum: 16 threads (same pr) are contiguous lanes within one wave
    #pragma unroll
    for (int o = 8; o; o >>= 1) lsum += __shfl_xor(lsum, o);
    if ((l & 15) == 0) lall[pr] = lsum;
    __syncthreads();
    #pragma unroll
    for (int t = 0; t < 4; t++){
        #pragma unroll
        for (int r = 0; r < 4; r++){
            int row = qrow[r];
            int col = cbase + t*16 + vcol[r];
            float v = (acc[t][0][r] + acc[t][1][r]) / lall[row];
            v = v > 0.f ? v : expm1f(v);   // elu
            res[(size_t)(i0 + row) * HIDD + col] = v;
        }
    }
}

// ---------------- GAT layer 2: round-8 green structure, bound-max ----------------
__global__ __launch_bounds__(256) void k_gat2(const int* __restrict__ adj,
        const float* __restrict__ o1, const float* __restrict__ o2,
        const float* __restrict__ t1, const float* __restrict__ t2,
        const float* __restrict__ o2max, const float* __restrict__ t2max,
        const ushort_t* __restrict__ V2h, const ushort_t* __restrict__ V2l,
        float* __restrict__ out2){
    __shared__ float accs[4][16][64];
    __shared__ float lsums[4][16];
    int i0 = blockIdx.x * 16;
    int tid = threadIdx.x;
    int w = tid >> 6, l = tid & 63, lm = l & 15, lh = l >> 4;
    int qrow[4], vcol[4];
    calib_cd(lm, qrow, vcol);
    int jbase = w * (NNODE / 4);
    float o1v = o1[i0 + lm], t1v = t1[i0 + lm];
    float M = lrelu(o1v + *o2max) + lrelu(t1v + *t2max);  // exact upper bound
    float lsum = 0.f;
    f32x4 acc[4] = {};
    const int*   adjp = adj + (size_t)(i0 + lm) * NNODE + jbase + lh * 8;
    const float* o2p  = o2 + jbase + lh * 8;
    const float* t2p  = t2 + jbase + lh * 8;

    for (int js = 0; js < NNODE/4; js += 32){
        int4 a0 = *(const int4*)(adjp + js);
        int4 a1 = *(const int4*)(adjp + js + 4);
        float4 ov0 = *(const float4*)(o2p + js), ov1 = *(const float4*)(o2p + js + 4);
        float4 tv0 = *(const float4*)(t2p + js), tv1 = *(const float4*)(t2p + js + 4);
        int   av[8]  = {a0.x, a0.y, a0.z, a0.w, a1.x, a1.y, a1.z, a1.w};
        float o2a[8] = {ov0.x, ov0.y, ov0.z, ov0.w, ov1.x, ov1.y, ov1.z, ov1.w};
        float t2a[8] = {tv0.x, tv0.y, tv0.z, tv0.w, tv1.x, tv1.y, tv1.z, tv1.w};
        bf16x8 pkh, pkl;
        #pragma unroll
        for (int e = 0; e < 8; e++){
            float p = 0.f;
            if (av[e] > 0) p = expf(lrelu(o1v + o2a[e]) + lrelu(t1v + t2a[e]) - M);
            lsum += p;
            ushort_t h, lo; split2(p, h, lo);
            ((ushort_t*)&pkh)[e] = h; ((ushort_t*)&pkl)[e] = lo;
        }
        #pragma unroll
        for (int t = 0; t < 4; t++){
            size_t boff = (size_t)(t*16 + lm) * NNODE + jbase + js + lh * 8;
            bf16x8 vh = *(const bf16x8*)(V2h + boff);
            bf16x8 vl = *(const bf16x8*)(V2l + boff);
            acc[t] = __builtin_amdgcn_mfma_f32_16x16x32_bf16(pkh, vh, acc[t], 0, 0, 0);
            acc[t] = __builtin_amdgcn_mfma_f32_16x16x32_bf16(pkh, vl, acc[t], 0, 0, 0);
            acc[t] = __builtin_amdgcn_mfma_f32_16x16x32_bf16(pkl, vh, acc[t], 0, 0, 0);
        }
    }
    lsum += __shfl_xor(lsum, 16);
    lsum += __shfl_xor(lsum, 32);
    if (lh == 0) lsums[w][lm] = lsum;
    #pragma unroll
    for (int t = 0; t < 4; t++)
        #pragma unroll
        for (int r = 0; r < 4; r++)
            accs[w][qrow[r]][t*16 + vcol[r]] = acc[t][r];
    __syncthreads();
    #pragma unroll
    for (int rr = 0; rr < 4; rr++){
        int row = w * 4 + rr;
        float den = lsums[0][row] + lsums[1][row] + lsums[2][row] + lsums[3][row];
        float v = (accs[0][row][l] + accs[1][row][l] + accs[2][row][l] + accs[3][row][l]) / den;
        out2[(size_t)(i0 + row) * NCLSD + l] = v;
    }
}

// ---------------- row-wise log_softmax over 64 classes ----------------
__global__ void k_logsoftmax(const float* __restrict__ out2, float* __restrict__ out){
    int w = threadIdx.x >> 6, l = threadIdx.x & 63;
    int row = blockIdx.x * 4 + w;
    float v = out2[(size_t)row * NCLSD + l];
    float mx = v;
    #pragma unroll
    for (int o = 32; o; o >>= 1) mx = fmaxf(mx, __shfl_xor(mx, o));
    float ex = expf(v - mx);
    #pragma unroll
    for (int o = 32; o; o >>= 1) ex += __shfl_xor(ex, o);
    out[(size_t)row * NCLSD + l] = v - mx - logf(ex);
}

// ---------------- launch ----------------
extern "C" void kernel_launch(void* const* d_in, const int* in_sizes, int n_in,
                              void* d_out, int out_size, void* d_ws, size_t ws_size,
                              hipStream_t stream){
    const float* X   = (const float*)d_in[0];
    const int*   adj = (const int*)d_in[1];
    const float* Wg  = (const float*)d_in[2];
    const float* ag  = (const float*)d_in[3];
    const float* Wt  = (const float*)d_in[4];
    const float* at  = (const float*)d_in[5];
    const float* Wo  = (const float*)d_in[6];
    const float* ao  = (const float*)d_in[7];
    float* out = (float*)d_out;

    char* ws = (char*)d_ws;
    size_t off = 0;
    auto take = [&](size_t n){ char* p = ws + off; off = (off + n + 255) & ~(size_t)255; return p; };
    ushort_t* WhTh  = (ushort_t*)take((size_t)HIDD * NNODE * 2);
    ushort_t* WhTl  = (ushort_t*)take((size_t)HIDD * NNODE * 2);
    float*    res   = (float*)take((size_t)NNODE * HIDD * 4);
    float*    Wh2   = (float*)take((size_t)NNODE * NCLSD * 4);
    ushort_t* Wh2Th = (ushort_t*)take((size_t)NCLSD * NNODE * 2);
    ushort_t* Wh2Tl = (ushort_t*)take((size_t)NCLSD * NNODE * 2);
    ushort_t* WgTh  = (ushort_t*)take((size_t)HIDD * FEATD * 2);
    ushort_t* WgTl  = (ushort_t*)take((size_t)HIDD * FEATD * 2);
    float* e1v  = (float*)take(NNODE * 4);
    float* e2v  = (float*)take(NNODE * 4);
    float* t1v  = (float*)take(NNODE * 4);
    float* t2v  = (float*)take(NNODE * 4);
    float* o1v  = (float*)take(NNODE * 4);
    float* o2v  = (float*)take(NNODE * 4);
    float* wg1  = (float*)take(FEATD * 4);
    float* wg2  = (float*)take(FEATD * 4);
    float* wt1  = (float*)take(HIDD * 4);
    float* wt2  = (float*)take(HIDD * 4);
    float* scal = (float*)take(256);
    float* e2m = scal, * t2m = scal + 1, * o2m = scal + 2;
    float* out2 = Wh2;  // alias: gat2 reads only Wh2T/vectors, writes out2

    // weight prep
    k_transpose_split<<<dim3((FEATD*HIDD + 255)/256), dim3(256), 0, stream>>>(Wg, WgTh, WgTl, FEATD, HIDD);
    k_fold<<<dim3(FEATD/4), dim3(256), 0, stream>>>(Wg, ag, wg1, wg2, HIDD);
    k_fold<<<dim3(HIDD/4),  dim3(256), 0, stream>>>(Wt, at, wt1, wt2, HIDD);
    // layer-1 scores (folded, exact fp32 algebra)
    k_rowvec2_f32<<<dim3(NNODE/4), dim3(256), 0, stream>>>(X, wg1, wg2, e1v, e2v, FEATD);
    k_max<<<dim3(1), dim3(1024), 0, stream>>>(e2v, NNODE, e2m);
    // Wh1^T via MFMA (hi/lo)
    k_gemm_xw<<<dim3(NNODE/16), dim3(512), 0, stream>>>(X, WgTh, WgTl, WhTh, WhTl);
    // GAT layer 1
    k_gat1<<<dim3(NNODE/16 * 2), dim3(256), 0, stream>>>(adj, e1v, e2v, e2m, WhTh, WhTl, res);
    // tree scores via fold (replaces the res@Wt GEMM)
    k_rowvec2_f32<<<dim3(NNODE/4), dim3(256), 0, stream>>>(res, wt1, wt2, t1v, t2v, HIDD);
    k_max<<<dim3(1), dim3(1024), 0, stream>>>(t2v, NNODE, t2m);
    // layer-2 prep
    k_mm<<<dim3((NNODE*NCLSD)/256), dim3(256), 0, stream>>>(res, Wo, Wh2, NNODE, HIDD, NCLSD);
    k_rowvec2_f32<<<dim3(NNODE/4), dim3(256), 0, stream>>>(Wh2, ao, ao + NCLSD, o1v, o2v, NCLSD);
    k_max<<<dim3(1), dim3(1024), 0, stream>>>(o2v, NNODE, o2m);
    k_transpose_split<<<dim3((NNODE*NCLSD + 255)/256), dim3(256), 0, stream>>>(Wh2, Wh2Th, Wh2Tl, NNODE, NCLSD);
    // GAT layer 2 (+bound-max) and log_softmax
    k_gat2<<<dim3(NNODE/16), dim3(256), 0, stream>>>(adj, o1v, o2v, t1v, t2v, o2m, t2m, Wh2Th, Wh2Tl, out2);
    k_logsoftmax<<<dim3(NNODE/4), dim3(256), 0, stream>>>(out2, out);
}

// Round 10
// 599.154 us; speedup vs baseline: 39.5024x; 1.5846x over previous
//
#include <hip/hip_runtime.h>

#define NNODE 6144
#define FEATD 512
#define HIDD  512
#define NCLSD 64
#define NMSK  (NNODE/64)   // 96 mask words per row
#define LALPHA 0.2f

typedef unsigned short ushort_t;
typedef unsigned long long u64_t;
typedef short bf16x8 __attribute__((ext_vector_type(8)));
typedef float f32x4 __attribute__((ext_vector_type(4)));

__device__ __forceinline__ float lrelu(float x){ return x > 0.f ? x : LALPHA * x; }

__device__ __forceinline__ ushort_t f2b(float x){
    union { float f; unsigned u; } v; v.f = x;
    unsigned r = v.u + 0x7fffu + ((v.u >> 16) & 1u);
    return (ushort_t)(r >> 16);
}
__device__ __forceinline__ float b2f(ushort_t u){
    union { unsigned u; float f; } v; v.u = ((unsigned)u) << 16; return v.f;
}

// Runtime C/D-layout calibration (round-8 validated)
__device__ __forceinline__ void calib_cd(int lm, int* qrow, int* vcol){
    bf16x8 ai, as;
    ushort_t vi = f2b((float)(lm + 1));
    ushort_t vs = f2b(0.03125f);
    #pragma unroll
    for (int e = 0; e < 8; e++){ ((ushort_t*)&ai)[e] = vi; ((ushort_t*)&as)[e] = vs; }
    f32x4 z = {0.f, 0.f, 0.f, 0.f};
    f32x4 d1 = __builtin_amdgcn_mfma_f32_16x16x32_bf16(ai, as, z, 0, 0, 0);
    f32x4 d2 = __builtin_amdgcn_mfma_f32_16x16x32_bf16(as, ai, z, 0, 0, 0);
    #pragma unroll
    for (int r = 0; r < 4; r++){
        qrow[r] = (int)(d1[r] + 0.5f) - 1;
        vcol[r] = (int)(d2[r] + 0.5f) - 1;
    }
}

// ---------------- adj (int32) -> bitmask, one ballot per 64 entries ----------------
__global__ void k_adjmask(const int* __restrict__ adj, u64_t* __restrict__ mask){
    int lane = threadIdx.x & 63;
    size_t wid = ((size_t)blockIdx.x * blockDim.x + threadIdx.x) >> 6;
    size_t nw = (size_t)NNODE * NNODE / 64;
    size_t stride = ((size_t)gridDim.x * blockDim.x) >> 6;
    for (size_t q = wid; q < nw; q += stride){
        int a = adj[q * 64 + lane];
        u64_t b = __ballot(a > 0);
        if (lane == 0) mask[q] = b;
    }
}

// ---------------- C = A @ B (dumb fp32, small-output use only) ----------------
__global__ void k_mm(const float* __restrict__ A, const float* __restrict__ B,
                     float* __restrict__ C, int M, int K, int Nc){
    int idx = blockIdx.x * blockDim.x + threadIdx.x;
    if (idx >= M * Nc) return;
    int r = idx / Nc, c = idx - r * Nc;
    const float* a = A + (size_t)r * K;
    float acc = 0.f;
    for (int k = 0; k < K; k++) acc += a[k] * B[(size_t)k * Nc + c];
    C[idx] = acc;
}

// out1[r]=W[r]·a[0:K]; out2[r]=W[r]·a[K:2K]  (one wave per row)
__global__ void k_fold(const float* __restrict__ W, const float* __restrict__ a,
                       float* __restrict__ out1, float* __restrict__ out2, int K){
    int row  = (blockIdx.x * blockDim.x + threadIdx.x) >> 6;
    int lane = threadIdx.x & 63;
    const float* wr = W + (size_t)row * K;
    float s1 = 0.f, s2 = 0.f;
    for (int c = lane; c < K; c += 64){ float w = wr[c]; s1 += w * a[c]; s2 += w * a[K + c]; }
    #pragma unroll
    for (int m = 32; m; m >>= 1){ s1 += __shfl_xor(s1, m); s2 += __shfl_xor(s2, m); }
    if (lane == 0){ out1[row] = s1; out2[row] = s2; }
}

// ---------------- o1/o2 = A @ {v1,v2}  (one wave per row) ----------------
__global__ void k_rowvec2_f32(const float* __restrict__ A, const float* __restrict__ v1,
                              const float* __restrict__ v2, float* __restrict__ o1,
                              float* __restrict__ o2, int K){
    int row  = (blockIdx.x * blockDim.x + threadIdx.x) >> 6;
    int lane = threadIdx.x & 63;
    const float* r = A + (size_t)row * K;
    float s1 = 0.f, s2 = 0.f;
    for (int c = lane; c < K; c += 64){ float x = r[c]; s1 += x * v1[c]; s2 += x * v2[c]; }
    #pragma unroll
    for (int m = 32; m; m >>= 1){ s1 += __shfl_xor(s1, m); s2 += __shfl_xor(s2, m); }
    if (lane == 0){ o1[row] = s1; o2[row] = s2; }
}

// ---------------- dst[c*R + r] = bf16(src[r*C + c]) ----------------
__global__ void k_transpose_bf16(const float* __restrict__ src, ushort_t* __restrict__ dst,
                                 int R, int C){
    int idx = blockIdx.x * blockDim.x + threadIdx.x;
    if (idx >= R * C) return;
    int r = idx / C, c = idx - r * C;
    dst[(size_t)c * R + r] = f2b(src[idx]);
}

// ---------------- *out = max(x[0..n)) ----------------
__global__ void k_max(const float* __restrict__ x, int n, float* __restrict__ out){
    __shared__ float sm[16];
    float m = -3.0e38f;
    for (int i = threadIdx.x; i < n; i += blockDim.x) m = fmaxf(m, x[i]);
    #pragma unroll
    for (int s = 32; s; s >>= 1) m = fmaxf(m, __shfl_xor(m, s));
    if ((threadIdx.x & 63) == 0) sm[threadIdx.x >> 6] = m;
    __syncthreads();
    if (threadIdx.x == 0){
        float mm = sm[0];
        for (int i = 1; i < (int)(blockDim.x >> 6); i++) mm = fmaxf(mm, sm[i]);
        *out = mm;
    }
}

// ---------------- Wh1^T = (X @ Wg)^T  via MFMA, single bf16 ----------------
__global__ __launch_bounds__(512) void k_gemm_xw(const float* __restrict__ X,
        const ushort_t* __restrict__ B, ushort_t* __restrict__ WhT){
    int i0 = blockIdx.x * 16;
    int w = threadIdx.x >> 6, l = threadIdx.x & 63, lm = l & 15, lh = l >> 4;
    int c0 = w * 64;
    int qrow[4], vcol[4];
    calib_cd(lm, qrow, vcol);
    f32x4 acc[4] = {};
    const float* xp = X + (size_t)(i0 + lm) * FEATD + lh * 8;
    for (int k0 = 0; k0 < FEATD; k0 += 32){
        bf16x8 af;
        #pragma unroll
        for (int e = 0; e < 8; e++) ((ushort_t*)&af)[e] = f2b(xp[k0 + e]);
        #pragma unroll
        for (int t = 0; t < 4; t++){
            bf16x8 bf = *(const bf16x8*)(B + (size_t)(c0 + t*16 + lm) * FEATD + k0 + lh * 8);
            acc[t] = __builtin_amdgcn_mfma_f32_16x16x32_bf16(af, bf, acc[t], 0, 0, 0);
        }
    }
    #pragma unroll
    for (int t = 0; t < 4; t++)
        #pragma unroll
        for (int r = 0; r < 4; r++)
            WhT[(size_t)(c0 + t*16 + vcol[r]) * NNODE + i0 + qrow[r]] = f2b(acc[t][r]);
}

// ---------------- GAT layer 1 v3: mask+e2 in LDS, single bf16, V prefetch ----------------
// 256 thr (4 waves); block = (rg, ch): 16 rows x 256 cols; grid 768.
__global__ __launch_bounds__(256) void k_gat1(const u64_t* __restrict__ mask,
        const float* __restrict__ e1, const float* __restrict__ e2,
        const float* __restrict__ e2max,
        const ushort_t* __restrict__ V, float* __restrict__ res){
    __shared__ __align__(16) ushort_t P[2][16][72];
    __shared__ __align__(16) float e2s[NNODE];
    __shared__ u64_t msk[16][NMSK + 1];
    __shared__ float lall[16];
    int bid = blockIdx.x;
    int rg = bid >> 1, ch = bid & 1;
    int i0 = rg * 16;
    int tid = threadIdx.x;
    int l = tid & 63, lm = l & 15, lh = l >> 4;
    int cbase = ch * 256 + (tid >> 6) * 64;
    int pr = tid >> 4, jc = (tid & 15) * 4;
    int qrow[4], vcol[4];
    calib_cd(lm, qrow, vcol);
    // stage e2 + mask rows in LDS
    for (int k = tid; k < NNODE; k += 256) e2s[k] = e2[k];
    for (int k = tid; k < 16 * NMSK; k += 256) msk[k / NMSK][k % NMSK] = mask[(size_t)i0 * NMSK + k];
    __syncthreads();
    float e1i = e1[i0 + pr];
    float M = lrelu(e1i + *e2max);          // exact upper bound (softmax-invariant)
    float lsum = 0.f;
    f32x4 acc[4] = {};
    bf16x8 vc[4][2], vn[4][2];
    #pragma unroll
    for (int t = 0; t < 4; t++)
        #pragma unroll
        for (int h = 0; h < 2; h++)
            vc[t][h] = *(const bf16x8*)(V + (size_t)(cbase + t*16 + lm) * NNODE + h*32 + lh*8);

    for (int j0 = 0; j0 < NNODE; j0 += 64){
        int buf = (j0 >> 6) & 1;
        u64_t word = msk[pr][j0 >> 6];
        float4 f4 = *(const float4*)&e2s[j0 + jc];
        ushort_t pb[4];
        float ls = 0.f;
        #pragma unroll
        for (int k = 0; k < 4; k++){
            float p = ((word >> (jc + k)) & 1ull) ?
                      expf(lrelu(e1i + ((const float*)&f4)[k]) - M) : 0.f;
            pb[k] = f2b(p);
            ls += b2f(pb[k]);
        }
        lsum += ls;
        *(uint2*)&P[buf][pr][jc] = *(uint2*)pb;
        __syncthreads();
        bf16x8 a0 = *(const bf16x8*)&P[buf][lm][lh * 8];
        bf16x8 a1 = *(const bf16x8*)&P[buf][lm][32 + lh * 8];
        int j0n = j0 + 64;
        if (j0n < NNODE){
            #pragma unroll
            for (int t = 0; t < 4; t++)
                #pragma unroll
                for (int h = 0; h < 2; h++)
                    vn[t][h] = *(const bf16x8*)(V + (size_t)(cbase + t*16 + lm) * NNODE + j0n + h*32 + lh*8);
        }
        #pragma unroll
        for (int t = 0; t < 4; t++){
            acc[t] = __builtin_amdgcn_mfma_f32_16x16x32_bf16(a0, vc[t][0], acc[t], 0, 0, 0);
            acc[t] = __builtin_amdgcn_mfma_f32_16x16x32_bf16(a1, vc[t][1], acc[t], 0, 0, 0);
        }
        #pragma unroll
        for (int t = 0; t < 4; t++)
            #pragma unroll
            for (int h = 0; h < 2; h++)
                vc[t][h] = vn[t][h];
    }
    #pragma unroll
    for (int o = 8; o; o >>= 1) lsum += __shfl_xor(lsum, o);
    if ((l & 15) == 0) lall[pr] = lsum;
    __syncthreads();
    #pragma unroll
    for (int t = 0; t < 4; t++){
        #pragma unroll
        for (int r = 0; r < 4; r++){
            int row = qrow[r];
            int col = cbase + t*16 + vcol[r];
            float v = acc[t][r] / lall[row];
            v = v > 0.f ? v : expm1f(v);   // elu
            res[(size_t)(i0 + row) * HIDD + col] = v;
        }
    }
}

// ---------------- GAT layer 2 v2: 8-wave j-split, barrier-free loop, mask LDS ----------------
#define JSPAN (NNODE/8)
__global__ __launch_bounds__(512) void k_gat2(const u64_t* __restrict__ mask,
        const float* __restrict__ o1, const float* __restrict__ o2,
        const float* __restrict__ t1, const float* __restrict__ t2,
        const float* __restrict__ o2max, const float* __restrict__ t2max,
        const ushort_t* __restrict__ V2, float* __restrict__ out2){
    __shared__ float accs[8][16][64];
    __shared__ float lsums[8][16];
    __shared__ u64_t msk[16][NMSK + 1];
    int i0 = blockIdx.x * 16;
    int tid = threadIdx.x;
    int w = tid >> 6, l = tid & 63, lm = l & 15, lh = l >> 4;
    for (int k = tid; k < 16 * NMSK; k += 512) msk[k / NMSK][k % NMSK] = mask[(size_t)i0 * NMSK + k];
    __syncthreads();
    int qrow[4], vcol[4];
    calib_cd(lm, qrow, vcol);
    int jbase = w * JSPAN;
    float o1v = o1[i0 + lm], t1v = t1[i0 + lm];
    float M = lrelu(o1v + *o2max) + lrelu(t1v + *t2max);
    float lsum = 0.f;
    f32x4 acc[4] = {};
    const float* o2p = o2 + jbase + lh * 8;
    const float* t2p = t2 + jbase + lh * 8;
    float4 oA = *(const float4*)(o2p), oB = *(const float4*)(o2p + 4);
    float4 tA = *(const float4*)(t2p), tB = *(const float4*)(t2p + 4);
    bf16x8 vcur[4], vnxt[4];
    #pragma unroll
    for (int t = 0; t < 4; t++)
        vcur[t] = *(const bf16x8*)(V2 + (size_t)(t*16 + lm) * NNODE + jbase + lh * 8);

    for (int js = 0; js < JSPAN; js += 32){
        u64_t w64 = msk[lm][(jbase + js) >> 6];
        int sh = (js + lh * 8) & 63;
        float oa[8] = {oA.x, oA.y, oA.z, oA.w, oB.x, oB.y, oB.z, oB.w};
        float ta[8] = {tA.x, tA.y, tA.z, tA.w, tB.x, tB.y, tB.z, tB.w};
        bf16x8 pk;
        float ls = 0.f;
        #pragma unroll
        for (int e = 0; e < 8; e++){
            float p = ((w64 >> (sh + e)) & 1ull) ?
                      expf(lrelu(o1v + oa[e]) + lrelu(t1v + ta[e]) - M) : 0.f;
            ushort_t pb = f2b(p);
            ((ushort_t*)&pk)[e] = pb;
            ls += b2f(pb);
        }
        lsum += ls;
        int jn = js + 32;
        if (jn < JSPAN){
            oA = *(const float4*)(o2p + jn); oB = *(const float4*)(o2p + jn + 4);
            tA = *(const float4*)(t2p + jn); tB = *(const float4*)(t2p + jn + 4);
            #pragma unroll
            for (int t = 0; t < 4; t++)
                vnxt[t] = *(const bf16x8*)(V2 + (size_t)(t*16 + lm) * NNODE + jbase + jn + lh * 8);
        }
        #pragma unroll
        for (int t = 0; t < 4; t++)
            acc[t] = __builtin_amdgcn_mfma_f32_16x16x32_bf16(pk, vcur[t], acc[t], 0, 0, 0);
        #pragma unroll
        for (int t = 0; t < 4; t++) vcur[t] = vnxt[t];
    }
    lsum += __shfl_xor(lsum, 16);
    lsum += __shfl_xor(lsum, 32);
    if (lh == 0) lsums[w][lm] = lsum;
    #pragma unroll
    for (int t = 0; t < 4; t++)
        #pragma unroll
        for (int r = 0; r < 4; r++)
            accs[w][qrow[r]][t*16 + vcol[r]] = acc[t][r];
    __syncthreads();
    #pragma unroll
    for (int rr = 0; rr < 2; rr++){
        int row = w * 2 + rr;
        float den = 0.f, v = 0.f;
        #pragma unroll
        for (int q = 0; q < 8; q++){ den += lsums[q][row]; v += accs[q][row][l]; }
        out2[(size_t)(i0 + row) * NCLSD + l] = v / den;
    }
}

// ---------------- row-wise log_softmax over 64 classes ----------------
__global__ void k_logsoftmax(const float* __restrict__ out2, float* __restrict__ out){
    int w = threadIdx.x >> 6, l = threadIdx.x & 63;
    int row = blockIdx.x * 4 + w;
    float v = out2[(size_t)row * NCLSD + l];
    float mx = v;
    #pragma unroll
    for (int o = 32; o; o >>= 1) mx = fmaxf(mx, __shfl_xor(mx, o));
    float ex = expf(v - mx);
    #pragma unroll
    for (int o = 32; o; o >>= 1) ex += __shfl_xor(ex, o);
    out[(size_t)row * NCLSD + l] = v - mx - logf(ex);
}

// ---------------- launch ----------------
extern "C" void kernel_launch(void* const* d_in, const int* in_sizes, int n_in,
                              void* d_out, int out_size, void* d_ws, size_t ws_size,
                              hipStream_t stream){
    const float* X   = (const float*)d_in[0];
    const int*   adj = (const int*)d_in[1];
    const float* Wg  = (const float*)d_in[2];
    const float* ag  = (const float*)d_in[3];
    const float* Wt  = (const float*)d_in[4];
    const float* at  = (const float*)d_in[5];
    const float* Wo  = (const float*)d_in[6];
    const float* ao  = (const float*)d_in[7];
    float* out = (float*)d_out;

    char* ws = (char*)d_ws;
    size_t off = 0;
    auto take = [&](size_t n){ char* p = ws + off; off = (off + n + 255) & ~(size_t)255; return p; };
    u64_t*    maskb = (u64_t*)take((size_t)NNODE * NMSK * 8);        // 4.72 MB
    ushort_t* WhT   = (ushort_t*)take((size_t)HIDD * NNODE * 2);     // 6.29 MB
    float*    res   = (float*)take((size_t)NNODE * HIDD * 4);        // 12.58 MB
    float*    Wh2   = (float*)take((size_t)NNODE * NCLSD * 4);       // 1.57 MB
    ushort_t* Wh2T  = (ushort_t*)take((size_t)NCLSD * NNODE * 2);    // 0.79 MB
    ushort_t* WgT   = (ushort_t*)take((size_t)FEATD * HIDD * 2);     // 0.52 MB
    float* e1v  = (float*)take(NNODE * 4);
    float* e2v  = (float*)take(NNODE * 4);
    float* t1v  = (float*)take(NNODE * 4);
    float* t2v  = (float*)take(NNODE * 4);
    float* o1v  = (float*)take(NNODE * 4);
    float* o2v  = (float*)take(NNODE * 4);
    float* wg1  = (float*)take(FEATD * 4);
    float* wg2  = (float*)take(FEATD * 4);
    float* wt1  = (float*)take(HIDD * 4);
    float* wt2  = (float*)take(HIDD * 4);
    float* scal = (float*)take(256);
    float* e2m = scal, * t2m = scal + 1, * o2m = scal + 2;
    float* out2 = Wh2;   // alias: gat2 reads only Wh2T/vectors

    // adj -> bitmask (reads adj once)
    k_adjmask<<<dim3(2048), dim3(256), 0, stream>>>(adj, maskb);
    // weight prep
    k_transpose_bf16<<<dim3((FEATD*HIDD + 255)/256), dim3(256), 0, stream>>>(Wg, WgT, FEATD, HIDD);
    k_fold<<<dim3(FEATD/4), dim3(256), 0, stream>>>(Wg, ag, wg1, wg2, HIDD);
    k_fold<<<dim3(HIDD/4),  dim3(256), 0, stream>>>(Wt, at, wt1, wt2, HIDD);
    // layer-1 scores (exact fp32 fold)
    k_rowvec2_f32<<<dim3(NNODE/4), dim3(256), 0, stream>>>(X, wg1, wg2, e1v, e2v, FEATD);
    k_max<<<dim3(1), dim3(1024), 0, stream>>>(e2v, NNODE, e2m);
    // Wh1^T via MFMA (single bf16)
    k_gemm_xw<<<dim3(NNODE/16), dim3(512), 0, stream>>>(X, WgT, WhT);
    // GAT layer 1
    k_gat1<<<dim3(NNODE/16 * 2), dim3(256), 0, stream>>>(maskb, e1v, e2v, e2m, WhT, res);
    // tree scores via fold
    k_rowvec2_f32<<<dim3(NNODE/4), dim3(256), 0, stream>>>(res, wt1, wt2, t1v, t2v, HIDD);
    k_max<<<dim3(1), dim3(1024), 0, stream>>>(t2v, NNODE, t2m);
    // layer-2 prep
    k_mm<<<dim3((NNODE*NCLSD)/256), dim3(256), 0, stream>>>(res, Wo, Wh2, NNODE, HIDD, NCLSD);
    k_rowvec2_f32<<<dim3(NNODE/4), dim3(256), 0, stream>>>(Wh2, ao, ao + NCLSD, o1v, o2v, NCLSD);
    k_max<<<dim3(1), dim3(1024), 0, stream>>>(o2v, NNODE, o2m);
    k_transpose_bf16<<<dim3((NNODE*NCLSD + 255)/256), dim3(256), 0, stream>>>(Wh2, Wh2T, NNODE, NCLSD);
    // GAT layer 2 + log_softmax
    k_gat2<<<dim3(NNODE/16), dim3(512), 0, stream>>>(maskb, o1v, o2v, t1v, t2v, o2m, t2m, Wh2T, out2);
    k_logsoftmax<<<dim3(NNODE/4), dim3(256), 0, stream>>>(out2, out);
}

// Round 11
// 468.719 us; speedup vs baseline: 50.4951x; 1.2783x over previous
//
#include <hip/hip_runtime.h>

#define NNODE 6144
#define FEATD 512
#define HIDD  512
#define NCLSD 64
#define NMSK  (NNODE/64)   // 96 mask words per row
#define LALPHA 0.2f

typedef unsigned short ushort_t;
typedef unsigned long long u64_t;
typedef short bf16x8 __attribute__((ext_vector_type(8)));
typedef float f32x4 __attribute__((ext_vector_type(4)));

__device__ __forceinline__ float lrelu(float x){ return x > 0.f ? x : LALPHA * x; }

__device__ __forceinline__ ushort_t f2b(float x){
    union { float f; unsigned u; } v; v.f = x;
    unsigned r = v.u + 0x7fffu + ((v.u >> 16) & 1u);
    return (ushort_t)(r >> 16);
}
__device__ __forceinline__ float b2f(ushort_t u){
    union { unsigned u; float f; } v; v.u = ((unsigned)u) << 16; return v.f;
}

// Runtime C/D-layout calibration (round-8 validated)
__device__ __forceinline__ void calib_cd(int lm, int* qrow, int* vcol){
    bf16x8 ai, as;
    ushort_t vi = f2b((float)(lm + 1));
    ushort_t vs = f2b(0.03125f);
    #pragma unroll
    for (int e = 0; e < 8; e++){ ((ushort_t*)&ai)[e] = vi; ((ushort_t*)&as)[e] = vs; }
    f32x4 z = {0.f, 0.f, 0.f, 0.f};
    f32x4 d1 = __builtin_amdgcn_mfma_f32_16x16x32_bf16(ai, as, z, 0, 0, 0);
    f32x4 d2 = __builtin_amdgcn_mfma_f32_16x16x32_bf16(as, ai, z, 0, 0, 0);
    #pragma unroll
    for (int r = 0; r < 4; r++){
        qrow[r] = (int)(d1[r] + 0.5f) - 1;
        vcol[r] = (int)(d2[r] + 0.5f) - 1;
    }
}

// ---------------- adj (int32) -> bitmask ----------------
__global__ void k_adjmask(const int* __restrict__ adj, u64_t* __restrict__ mask){
    int lane = threadIdx.x & 63;
    size_t wid = ((size_t)blockIdx.x * blockDim.x + threadIdx.x) >> 6;
    size_t nw = (size_t)NNODE * NNODE / 64;
    size_t stride = ((size_t)gridDim.x * blockDim.x) >> 6;
    for (size_t q = wid; q < nw; q += stride){
        int a = adj[q * 64 + lane];
        u64_t b = __ballot(a > 0);
        if (lane == 0) mask[q] = b;
    }
}

// out1[r]=W[r]·a[0:K]; out2[r]=W[r]·a[K:2K]  (one wave per row)
__global__ void k_fold(const float* __restrict__ W, const float* __restrict__ a,
                       float* __restrict__ out1, float* __restrict__ out2, int K){
    int row  = (blockIdx.x * blockDim.x + threadIdx.x) >> 6;
    int lane = threadIdx.x & 63;
    const float* wr = W + (size_t)row * K;
    float s1 = 0.f, s2 = 0.f;
    for (int c = lane; c < K; c += 64){ float w = wr[c]; s1 += w * a[c]; s2 += w * a[K + c]; }
    #pragma unroll
    for (int m = 32; m; m >>= 1){ s1 += __shfl_xor(s1, m); s2 += __shfl_xor(s2, m); }
    if (lane == 0){ out1[row] = s1; out2[row] = s2; }
}

// ---------------- o1/o2 = A @ {v1,v2}  (one wave per row) ----------------
__global__ void k_rowvec2_f32(const float* __restrict__ A, const float* __restrict__ v1,
                              const float* __restrict__ v2, float* __restrict__ o1,
                              float* __restrict__ o2, int K){
    int row  = (blockIdx.x * blockDim.x + threadIdx.x) >> 6;
    int lane = threadIdx.x & 63;
    const float* r = A + (size_t)row * K;
    float s1 = 0.f, s2 = 0.f;
    for (int c = lane; c < K; c += 64){ float x = r[c]; s1 += x * v1[c]; s2 += x * v2[c]; }
    #pragma unroll
    for (int m = 32; m; m >>= 1){ s1 += __shfl_xor(s1, m); s2 += __shfl_xor(s2, m); }
    if (lane == 0){ o1[row] = s1; o2[row] = s2; }
}

// ---------------- dst[c*R + r] = bf16(src[r*C + c]) ----------------
__global__ void k_transpose_bf16(const float* __restrict__ src, ushort_t* __restrict__ dst,
                                 int R, int C){
    int idx = blockIdx.x * blockDim.x + threadIdx.x;
    if (idx >= R * C) return;
    int r = idx / C, c = idx - r * C;
    dst[(size_t)c * R + r] = f2b(src[idx]);
}

// ---------------- *out = max(x[0..n)) ----------------
__global__ void k_max(const float* __restrict__ x, int n, float* __restrict__ out){
    __shared__ float sm[16];
    float m = -3.0e38f;
    for (int i = threadIdx.x; i < n; i += blockDim.x) m = fmaxf(m, x[i]);
    #pragma unroll
    for (int s = 32; s; s >>= 1) m = fmaxf(m, __shfl_xor(m, s));
    if ((threadIdx.x & 63) == 0) sm[threadIdx.x >> 6] = m;
    __syncthreads();
    if (threadIdx.x == 0){
        float mm = sm[0];
        for (int i = 1; i < (int)(blockDim.x >> 6); i++) mm = fmaxf(mm, sm[i]);
        *out = mm;
    }
}

// ---------------- Wh1^T = (X @ Wg)^T  via MFMA, single bf16 ----------------
__global__ __launch_bounds__(512) void k_gemm_xw(const float* __restrict__ X,
        const ushort_t* __restrict__ B, ushort_t* __restrict__ WhT){
    int i0 = blockIdx.x * 16;
    int w = threadIdx.x >> 6, l = threadIdx.x & 63, lm = l & 15, lh = l >> 4;
    int c0 = w * 64;
    int qrow[4], vcol[4];
    calib_cd(lm, qrow, vcol);
    f32x4 acc[4] = {};
    const float* xp = X + (size_t)(i0 + lm) * FEATD + lh * 8;
    for (int k0 = 0; k0 < FEATD; k0 += 32){
        bf16x8 af;
        #pragma unroll
        for (int e = 0; e < 8; e++) ((ushort_t*)&af)[e] = f2b(xp[k0 + e]);
        #pragma unroll
        for (int t = 0; t < 4; t++){
            bf16x8 bf = *(const bf16x8*)(B + (size_t)(c0 + t*16 + lm) * FEATD + k0 + lh * 8);
            acc[t] = __builtin_amdgcn_mfma_f32_16x16x32_bf16(af, bf, acc[t], 0, 0, 0);
        }
    }
    #pragma unroll
    for (int t = 0; t < 4; t++)
        #pragma unroll
        for (int r = 0; r < 4; r++)
            WhT[(size_t)(c0 + t*16 + vcol[r]) * NNODE + i0 + qrow[r]] = f2b(acc[t][r]);
}

// ---------------- Wh2 = res @ Wo via MFMA; emits fp32 Wh2 + bf16 Wh2^T ----------------
// 256 thr (4 waves), each wave 16 rows x 64 cols (all classes); grid NNODE/64.
__global__ __launch_bounds__(256) void k_gemm_out(const float* __restrict__ res,
        const ushort_t* __restrict__ BT, float* __restrict__ Wh2, ushort_t* __restrict__ Wh2T){
    int w = threadIdx.x >> 6, l = threadIdx.x & 63, lm = l & 15, lh = l >> 4;
    int i0 = blockIdx.x * 64 + w * 16;
    int qrow[4], vcol[4];
    calib_cd(lm, qrow, vcol);
    f32x4 acc[4] = {};
    const float* ap = res + (size_t)(i0 + lm) * HIDD + lh * 8;
    for (int k0 = 0; k0 < HIDD; k0 += 32){
        bf16x8 af;
        #pragma unroll
        for (int e = 0; e < 8; e++) ((ushort_t*)&af)[e] = f2b(ap[k0 + e]);
        #pragma unroll
        for (int t = 0; t < 4; t++){
            bf16x8 bf = *(const bf16x8*)(BT + (size_t)(t*16 + lm) * HIDD + k0 + lh * 8);
            acc[t] = __builtin_amdgcn_mfma_f32_16x16x32_bf16(af, bf, acc[t], 0, 0, 0);
        }
    }
    #pragma unroll
    for (int t = 0; t < 4; t++){
        #pragma unroll
        for (int r = 0; r < 4; r++){
            int row = i0 + qrow[r], col = t*16 + vcol[r];
            float v = acc[t][r];
            Wh2[(size_t)row * NCLSD + col] = v;
            Wh2T[(size_t)col * NNODE + row] = f2b(v);
        }
    }
}

// ---------------- GAT layer 1 v4: register P, barrier-free loop ----------------
// 256 thr (4 waves); block = (rg, ch): 16 rows x 256 cols; grid 768.
__global__ __launch_bounds__(256) void k_gat1(const u64_t* __restrict__ mask,
        const float* __restrict__ e1, const float* __restrict__ e2,
        const float* __restrict__ e2max,
        const ushort_t* __restrict__ V, float* __restrict__ res){
    __shared__ __align__(16) float e2s[NNODE];
    __shared__ u64_t msk[16][NMSK + 1];
    int bid = blockIdx.x;
    int rg = bid >> 1, ch = bid & 1;
    int i0 = rg * 16;
    int tid = threadIdx.x;
    int w = tid >> 6, l = tid & 63, lm = l & 15, lh = l >> 4;
    int cbase = ch * 256 + w * 64;
    int qrow[4], vcol[4];
    calib_cd(lm, qrow, vcol);
    for (int k = tid; k < NNODE; k += 256) e2s[k] = e2[k];
    for (int k = tid; k < 16 * NMSK; k += 256) msk[k / NMSK][k % NMSK] = mask[(size_t)i0 * NMSK + k];
    __syncthreads();
    float e1i = e1[i0 + lm];              // this lane's P row = lm
    float M = lrelu(e1i + *e2max);        // exact upper bound (softmax-invariant)
    float lsum = 0.f;
    f32x4 acc[4] = {};
    const ushort_t* vb[4];
    #pragma unroll
    for (int t = 0; t < 4; t++) vb[t] = V + (size_t)(cbase + t*16 + lm) * NNODE + lh * 8;
    bf16x8 vc[4][2], vn[4][2];
    #pragma unroll
    for (int t = 0; t < 4; t++)
        #pragma unroll
        for (int h = 0; h < 2; h++) vc[t][h] = *(const bf16x8*)(vb[t] + h*32);

    for (int j0 = 0; j0 < NNODE; j0 += 64){
        u64_t word = msk[lm][j0 >> 6];
        int jn = j0 + 64;
        if (jn < NNODE){
            #pragma unroll
            for (int t = 0; t < 4; t++)
                #pragma unroll
                for (int h = 0; h < 2; h++) vn[t][h] = *(const bf16x8*)(vb[t] + jn + h*32);
        }
        #pragma unroll
        for (int h = 0; h < 2; h++){
            int jb = j0 + h*32 + lh*8;
            float4 fA = *(const float4*)&e2s[jb];
            float4 fB = *(const float4*)&e2s[jb + 4];
            float ea[8] = {fA.x, fA.y, fA.z, fA.w, fB.x, fB.y, fB.z, fB.w};
            int sh = h*32 + lh*8;
            bf16x8 pk;
            float ls = 0.f;
            #pragma unroll
            for (int e = 0; e < 8; e++){
                float p = ((word >> (sh + e)) & 1ull) ? __expf(lrelu(e1i + ea[e]) - M) : 0.f;
                ushort_t pb = f2b(p);
                ((ushort_t*)&pk)[e] = pb;
                ls += b2f(pb);
            }
            lsum += ls;
            #pragma unroll
            for (int t = 0; t < 4; t++)
                acc[t] = __builtin_amdgcn_mfma_f32_16x16x32_bf16(pk, vc[t][h], acc[t], 0, 0, 0);
        }
        #pragma unroll
        for (int t = 0; t < 4; t++)
            #pragma unroll
            for (int h = 0; h < 2; h++) vc[t][h] = vn[t][h];
    }
    // row sums: lanes {l, l^16, l^32, l^48} share row lm
    lsum += __shfl_xor(lsum, 16);
    lsum += __shfl_xor(lsum, 32);
    #pragma unroll
    for (int t = 0; t < 4; t++){
        #pragma unroll
        for (int r = 0; r < 4; r++){
            float den = __shfl(lsum, qrow[r]);   // lane qrow[r] holds row qrow[r]'s sum
            int row = qrow[r];
            int col = cbase + t*16 + vcol[r];
            float v = acc[t][r] / den;
            v = v > 0.f ? v : expm1f(v);   // elu
            res[(size_t)(i0 + row) * HIDD + col] = v;
        }
    }
}

// ---------------- GAT layer 2: 8-wave j-split, barrier-free loop ----------------
#define JSPAN (NNODE/8)
__global__ __launch_bounds__(512) void k_gat2(const u64_t* __restrict__ mask,
        const float* __restrict__ o1, const float* __restrict__ o2,
        const float* __restrict__ t1, const float* __restrict__ t2,
        const float* __restrict__ o2max, const float* __restrict__ t2max,
        const ushort_t* __restrict__ V2, float* __restrict__ out2){
    __shared__ float accs[8][16][64];
    __shared__ float lsums[8][16];
    __shared__ u64_t msk[16][NMSK + 1];
    int i0 = blockIdx.x * 16;
    int tid = threadIdx.x;
    int w = tid >> 6, l = tid & 63, lm = l & 15, lh = l >> 4;
    for (int k = tid; k < 16 * NMSK; k += 512) msk[k / NMSK][k % NMSK] = mask[(size_t)i0 * NMSK + k];
    __syncthreads();
    int qrow[4], vcol[4];
    calib_cd(lm, qrow, vcol);
    int jbase = w * JSPAN;
    float o1v = o1[i0 + lm], t1v = t1[i0 + lm];
    float M = lrelu(o1v + *o2max) + lrelu(t1v + *t2max);
    float lsum = 0.f;
    f32x4 acc[4] = {};
    const float* o2p = o2 + jbase + lh * 8;
    const float* t2p = t2 + jbase + lh * 8;
    float4 oA = *(const float4*)(o2p), oB = *(const float4*)(o2p + 4);
    float4 tA = *(const float4*)(t2p), tB = *(const float4*)(t2p + 4);
    bf16x8 vcur[4], vnxt[4];
    #pragma unroll
    for (int t = 0; t < 4; t++)
        vcur[t] = *(const bf16x8*)(V2 + (size_t)(t*16 + lm) * NNODE + jbase + lh * 8);

    for (int js = 0; js < JSPAN; js += 32){
        u64_t w64 = msk[lm][(jbase + js) >> 6];
        int sh = (js + lh * 8) & 63;
        float oa[8] = {oA.x, oA.y, oA.z, oA.w, oB.x, oB.y, oB.z, oB.w};
        float ta[8] = {tA.x, tA.y, tA.z, tA.w, tB.x, tB.y, tB.z, tB.w};
        bf16x8 pk;
        float ls = 0.f;
        #pragma unroll
        for (int e = 0; e < 8; e++){
            float p = ((w64 >> (sh + e)) & 1ull) ?
                      __expf(lrelu(o1v + oa[e]) + lrelu(t1v + ta[e]) - M) : 0.f;
            ushort_t pb = f2b(p);
            ((ushort_t*)&pk)[e] = pb;
            ls += b2f(pb);
        }
        lsum += ls;
        int jn = js + 32;
        if (jn < JSPAN){
            oA = *(const float4*)(o2p + jn); oB = *(const float4*)(o2p + jn + 4);
            tA = *(const float4*)(t2p + jn); tB = *(const float4*)(t2p + jn + 4);
            #pragma unroll
            for (int t = 0; t < 4; t++)
                vnxt[t] = *(const bf16x8*)(V2 + (size_t)(t*16 + lm) * NNODE + jbase + jn + lh * 8);
        }
        #pragma unroll
        for (int t = 0; t < 4; t++)
            acc[t] = __builtin_amdgcn_mfma_f32_16x16x32_bf16(pk, vcur[t], acc[t], 0, 0, 0);
        #pragma unroll
        for (int t = 0; t < 4; t++) vcur[t] = vnxt[t];
    }
    lsum += __shfl_xor(lsum, 16);
    lsum += __shfl_xor(lsum, 32);
    if (lh == 0) lsums[w][lm] = lsum;
    #pragma unroll
    for (int t = 0; t < 4; t++)
        #pragma unroll
        for (int r = 0; r < 4; r++)
            accs[w][qrow[r]][t*16 + vcol[r]] = acc[t][r];
    __syncthreads();
    #pragma unroll
    for (int rr = 0; rr < 2; rr++){
        int row = w * 2 + rr;
        float den = 0.f, v = 0.f;
        #pragma unroll
        for (int q = 0; q < 8; q++){ den += lsums[q][row]; v += accs[q][row][l]; }
        out2[(size_t)(i0 + row) * NCLSD + l] = v / den;
    }
}

// ---------------- row-wise log_softmax over 64 classes ----------------
__global__ void k_logsoftmax(const float* __restrict__ out2, float* __restrict__ out){
    int w = threadIdx.x >> 6, l = threadIdx.x & 63;
    int row = blockIdx.x * 4 + w;
    float v = out2[(size_t)row * NCLSD + l];
    float mx = v;
    #pragma unroll
    for (int o = 32; o; o >>= 1) mx = fmaxf(mx, __shfl_xor(mx, o));
    float ex = __expf(v - mx);
    #pragma unroll
    for (int o = 32; o; o >>= 1) ex += __shfl_xor(ex, o);
    out[(size_t)row * NCLSD + l] = v - mx - logf(ex);
}

// ---------------- launch ----------------
extern "C" void kernel_launch(void* const* d_in, const int* in_sizes, int n_in,
                              void* d_out, int out_size, void* d_ws, size_t ws_size,
                              hipStream_t stream){
    const float* X   = (const float*)d_in[0];
    const int*   adj = (const int*)d_in[1];
    const float* Wg  = (const float*)d_in[2];
    const float* ag  = (const float*)d_in[3];
    const float* Wt  = (const float*)d_in[4];
    const float* at  = (const float*)d_in[5];
    const float* Wo  = (const float*)d_in[6];
    const float* ao  = (const float*)d_in[7];
    float* out = (float*)d_out;

    char* ws = (char*)d_ws;
    size_t off = 0;
    auto take = [&](size_t n){ char* p = ws + off; off = (off + n + 255) & ~(size_t)255; return p; };
    u64_t*    maskb = (u64_t*)take((size_t)NNODE * NMSK * 8);
    ushort_t* WhT   = (ushort_t*)take((size_t)HIDD * NNODE * 2);
    float*    res   = (float*)take((size_t)NNODE * HIDD * 4);
    float*    Wh2   = (float*)take((size_t)NNODE * NCLSD * 4);
    ushort_t* Wh2T  = (ushort_t*)take((size_t)NCLSD * NNODE * 2);
    ushort_t* WgT   = (ushort_t*)take((size_t)FEATD * HIDD * 2);
    ushort_t* WoT   = (ushort_t*)take((size_t)HIDD * NCLSD * 2);
    float* e1v  = (float*)take(NNODE * 4);
    float* e2v  = (float*)take(NNODE * 4);
    float* t1v  = (float*)take(NNODE * 4);
    float* t2v  = (float*)take(NNODE * 4);
    float* o1v  = (float*)take(NNODE * 4);
    float* o2v  = (float*)take(NNODE * 4);
    float* wg1  = (float*)take(FEATD * 4);
    float* wg2  = (float*)take(FEATD * 4);
    float* wt1  = (float*)take(HIDD * 4);
    float* wt2  = (float*)take(HIDD * 4);
    float* scal = (float*)take(256);
    float* e2m = scal, * t2m = scal + 1, * o2m = scal + 2;
    float* out2 = Wh2;   // alias: gat2 reads only Wh2T/vectors

    // adj -> bitmask (reads adj once)
    k_adjmask<<<dim3(2048), dim3(256), 0, stream>>>(adj, maskb);
    // weight prep
    k_transpose_bf16<<<dim3((FEATD*HIDD + 255)/256), dim3(256), 0, stream>>>(Wg, WgT, FEATD, HIDD);
    k_transpose_bf16<<<dim3((HIDD*NCLSD + 255)/256), dim3(256), 0, stream>>>(Wo, WoT, HIDD, NCLSD);
    k_fold<<<dim3(FEATD/4), dim3(256), 0, stream>>>(Wg, ag, wg1, wg2, HIDD);
    k_fold<<<dim3(HIDD/4),  dim3(256), 0, stream>>>(Wt, at, wt1, wt2, HIDD);
    // layer-1 scores (exact fp32 fold)
    k_rowvec2_f32<<<dim3(NNODE/4), dim3(256), 0, stream>>>(X, wg1, wg2, e1v, e2v, FEATD);
    k_max<<<dim3(1), dim3(1024), 0, stream>>>(e2v, NNODE, e2m);
    // Wh1^T via MFMA
    k_gemm_xw<<<dim3(NNODE/16), dim3(512), 0, stream>>>(X, WgT, WhT);
    // GAT layer 1
    k_gat1<<<dim3(NNODE/16 * 2), dim3(256), 0, stream>>>(maskb, e1v, e2v, e2m, WhT, res);
    // tree scores via fold
    k_rowvec2_f32<<<dim3(NNODE/4), dim3(256), 0, stream>>>(res, wt1, wt2, t1v, t2v, HIDD);
    k_max<<<dim3(1), dim3(1024), 0, stream>>>(t2v, NNODE, t2m);
    // layer-2 prep (MFMA; emits Wh2 fp32 + Wh2T bf16)
    k_gemm_out<<<dim3(NNODE/64), dim3(256), 0, stream>>>(res, WoT, Wh2, Wh2T);
    k_rowvec2_f32<<<dim3(NNODE/4), dim3(256), 0, stream>>>(Wh2, ao, ao + NCLSD, o1v, o2v, NCLSD);
    k_max<<<dim3(1), dim3(1024), 0, stream>>>(o2v, NNODE, o2m);
    // GAT layer 2 + log_softmax
    k_gat2<<<dim3(NNODE/16), dim3(512), 0, stream>>>(maskb, o1v, o2v, t1v, t2v, o2m, t2m, Wh2T, out2);
    k_logsoftmax<<<dim3(NNODE/4), dim3(256), 0, stream>>>(out2, out);
}